// Round 11
// baseline (228.951 us; speedup 1.0000x reference)
//
#include <hip/hip_runtime.h>
#include <hip/hip_bf16.h>

// Problem constants (B,S,M,D,H,DH = 2,1024,1024,1024,16,64)
#define B_ 2
#define S_ 1024
#define M_ 1024
#define D_ 1024
#define H_ 16
#define DH_ 64
#define K_ 2048
#define R_ 4095

// finite stand-in for -inf (avoids inf arithmetic under fast-math)
#define NEG_BIG (-1e30f)

typedef unsigned short u16;
typedef short short8 __attribute__((ext_vector_type(8)));
typedef float f32x4 __attribute__((ext_vector_type(4)));

__device__ __forceinline__ u16 f2bf(float f) {
  __hip_bfloat16 h = __float2bfloat16(f);
  return *reinterpret_cast<u16*>(&h);
}
__device__ __forceinline__ float bf2f(u16 u) {
  __hip_bfloat16 h;
  *reinterpret_cast<u16*>(&h) = u;
  return __bfloat162float(h);
}

// async global->LDS, 16B per lane; LDS dest = wave-uniform base + lane*16
__device__ __forceinline__ void gll16(const void* g, const void* l) {
  __builtin_amdgcn_global_load_lds(
      (const __attribute__((address_space(1))) unsigned int*)g,
      (__attribute__((address_space(3))) unsigned int*)l, 16, 0, 0);
}

__device__ __forceinline__ f32x4 mfma16(short8 a, short8 b, f32x4 c) {
  return __builtin_amdgcn_mfma_f32_16x16x32_bf16(a, b, c, 0, 0, 0);
}

// ---------------- fused prep: LN(concat) + 4x weight transpose + pos cvt ----------------
__global__ __launch_bounds__(256) void prep_kernel(
    const float* __restrict__ hidden, const float* __restrict__ memory,
    const float* __restrict__ gamma, const float* __restrict__ beta,
    u16* __restrict__ cln,
    const float* __restrict__ W0, const float* __restrict__ W1,
    const float* __restrict__ W2, const float* __restrict__ W3,
    u16* __restrict__ O0, u16* __restrict__ O1,
    u16* __restrict__ O2, u16* __restrict__ O3,
    const float* __restrict__ pos, u16* __restrict__ posb) {
  __shared__ u16 tile[64][66];
  __shared__ float red[8];
  const int bx = blockIdx.x;
  const int t = threadIdx.x;

  if (bx < 4096) {  // LayerNorm row
    const int b = bx >> 11;
    const int idx = bx & (K_ - 1);
    const float* src = (idx < M_)
        ? memory + (size_t)(b * M_ + idx) * D_
        : hidden + (size_t)(b * S_ + (idx - M_)) * D_;
    const int lane = t & 63, w = t >> 6;
    float4 rv = ((const float4*)src)[t];
    float s = rv.x + rv.y + rv.z + rv.w;
    float ss = rv.x * rv.x + rv.y * rv.y + rv.z * rv.z + rv.w * rv.w;
#pragma unroll
    for (int m = 1; m < 64; m <<= 1) {
      s += __shfl_xor(s, m, 64);
      ss += __shfl_xor(ss, m, 64);
    }
    if (lane == 0) { red[w] = s; red[4 + w] = ss; }
    __syncthreads();
    s = red[0] + red[1] + red[2] + red[3];
    ss = red[4] + red[5] + red[6] + red[7];
    const float mu = s * (1.0f / D_);
    const float var = ss * (1.0f / D_) - mu * mu;
    const float rstd = rsqrtf(var + 1e-5f);
    float4 gv = ((const float4*)gamma)[t];
    float4 bv = ((const float4*)beta)[t];
    ushort4 ov;
    ov.x = f2bf((rv.x - mu) * rstd * gv.x + bv.x);
    ov.y = f2bf((rv.y - mu) * rstd * gv.y + bv.y);
    ov.z = f2bf((rv.z - mu) * rstd * gv.z + bv.z);
    ov.w = f2bf((rv.w - mu) * rstd * gv.w + bv.w);
    ((ushort4*)(cln + (size_t)bx * D_))[t] = ov;
    return;
  }
  if (bx < 5120) {  // weight transpose slab
    const int z = (bx - 4096) >> 8;
    const int rem = (bx - 4096) & 255;
    const float* in; u16* out;
    switch (z) {
      case 0:  in = W0; out = O0; break;
      case 1:  in = W1; out = O1; break;
      case 2:  in = W2; out = O2; break;
      default: in = W3; out = O3; break;
    }
    const int tx = t & 63, ty = t >> 6;
    const int k0 = (rem & 15) * 64, n0 = (rem >> 4) * 64;
#pragma unroll
    for (int i = ty; i < 64; i += 4)
      tile[i][tx] = f2bf(in[(size_t)(k0 + i) * D_ + n0 + tx]);
    __syncthreads();
#pragma unroll
    for (int i = ty; i < 64; i += 4)
      out[(size_t)(n0 + i) * D_ + k0 + tx] = tile[tx][i];
    return;
  }
  // pos f32 -> bf16
  const int i = (bx - 5120) * 256 + t;
  const int n4 = B_ * R_ * 64 / 4;
  if (i < n4) {
    float4 v = ((const float4*)pos)[i];
    ushort4 o;
    o.x = f2bf(v.x); o.y = f2bf(v.y); o.z = f2bf(v.z); o.w = f2bf(v.w);
    ((ushort4*)posb)[i] = o;
  }
}

// row r of the "hidden slice" view -> row of c_ln
__device__ __forceinline__ int maprow_hidden(int r) {
  return r + ((r >> 10) << 10) + M_;
}

// ---------------- QKV GEMM: BK=64, XOR-swizzled staging, 16 barrier-pairs ----------------
__global__ __launch_bounds__(256, 2) void gemm_qkv_kernel(
    const u16* __restrict__ A, const u16* __restrict__ Bt,
    u16* __restrict__ qb, u16* __restrict__ kb, u16* __restrict__ vbT) {
  __shared__ __align__(16) u16 As[128 * 64];   // 16 KB
  __shared__ __align__(16) u16 Bs[128 * 64];   // 16 KB
  const int t = threadIdx.x;
  const int lane = t & 63, w = t >> 6;
  const int wm = w >> 1, wn = w & 1;
  const int qd = lane >> 4, lr = lane & 15;
  const int m0 = blockIdx.y * 128, n0 = blockIdx.x * 128;
  if (n0 < 1024 && !(m0 & 1024)) return;   // dead Q tiles (memory rows)

  const int swz = ((t & 7) ^ ((t >> 3) & 7)) * 8;  // source-chunk swizzle
  const int c0 = (qd ^ (lr & 7)) * 8;
  const int c1 = c0 ^ 32;
  const int row8 = (t >> 3) & 7;

  f32x4 acc[4][4];
#pragma unroll
  for (int mt = 0; mt < 4; mt++)
#pragma unroll
    for (int nt = 0; nt < 4; nt++) acc[mt][nt] = (f32x4){0.f, 0.f, 0.f, 0.f};

  for (int kt = 0; kt < 1024; kt += 64) {
#pragma unroll
    for (int p = 0; p < 4; p++) {
      const int ra = w * 32 + p * 8 + row8;
      gll16(A + (size_t)(m0 + ra) * 1024 + kt + swz, As + (w * 32 + p * 8) * 64);
      gll16(Bt + (size_t)(n0 + ra) * 1024 + kt + swz, Bs + (w * 32 + p * 8) * 64);
    }
    __syncthreads();
    short8 a0[4], a1[4], b0[4], b1[4];
#pragma unroll
    for (int mt = 0; mt < 4; mt++) {
      a0[mt] = *(const short8*)&As[(wm * 64 + mt * 16 + lr) * 64 + c0];
      a1[mt] = *(const short8*)&As[(wm * 64 + mt * 16 + lr) * 64 + c1];
    }
#pragma unroll
    for (int nt = 0; nt < 4; nt++) {
      b0[nt] = *(const short8*)&Bs[(wn * 64 + nt * 16 + lr) * 64 + c0];
      b1[nt] = *(const short8*)&Bs[(wn * 64 + nt * 16 + lr) * 64 + c1];
    }
#pragma unroll
    for (int mt = 0; mt < 4; mt++)
#pragma unroll
      for (int nt = 0; nt < 4; nt++) {
        acc[mt][nt] = mfma16(a0[mt], b0[nt], acc[mt][nt]);
        acc[mt][nt] = mfma16(a1[mt], b1[nt], acc[mt][nt]);
      }
    __syncthreads();
  }

#pragma unroll
  for (int mt = 0; mt < 4; mt++)
#pragma unroll
    for (int nt = 0; nt < 4; nt++) {
      const int colb = n0 + wn * 64 + nt * 16;
      const int rowb = m0 + wm * 64 + mt * 16 + qd * 4;
      if (colb < 1024) {                               // Q (pre-scaled 1/32)
        const int qrow = ((rowb >> 11) << 10) | (rowb & 1023);
#pragma unroll
        for (int r = 0; r < 4; r++)
          qb[(size_t)(qrow + r) * 1024 + colb + lr] = f2bf(acc[mt][nt][r] * 0.03125f);
      } else if (colb < 2048) {                        // K row-major
        const int key = rowb & (K_ - 1);
        const int bq = rowb >> 11;
#pragma unroll
        for (int r = 0; r < 4; r++)
          kb[(size_t)(bq * K_ + key + r) * 1024 + (colb - 1024) + lr] = f2bf(acc[mt][nt][r]);
      } else {                                         // V transposed [b*H+h][dh][key]
        const int nn = colb - 2048 + lr;
        const int bh = ((rowb >> 11) << 4) | (nn >> 6);
        const int dh = nn & 63;
        const int key = rowb & (K_ - 1);
        ushort4 pk;
        pk.x = f2bf(acc[mt][nt][0]);
        pk.y = f2bf(acc[mt][nt][1]);
        pk.z = f2bf(acc[mt][nt][2]);
        pk.w = f2bf(acc[mt][nt][3]);
        *(ushort4*)&vbT[((size_t)bh * 64 + dh) * K_ + key] = pk;
      }
    }
}

// ---------------- out GEMM: 128x64 tiles (256 blocks), f32 out + LN residual ----------------
__global__ __launch_bounds__(256, 2) void out_gemm_kernel(
    const u16* __restrict__ A, const u16* __restrict__ Bt,
    const u16* __restrict__ resid, float* __restrict__ Cf) {
  __shared__ __align__(16) u16 As[128 * 32];
  __shared__ __align__(16) u16 Bs[64 * 32];
  const int t = threadIdx.x;
  const int lane = t & 63, w = t >> 6;
  const int wm = w >> 1, wn = w & 1;
  const int qd = lane >> 4, lr = lane & 15;
  const int m0 = blockIdx.y * 128, n0 = blockIdx.x * 64;

  const u16* Ag0 = A + (size_t)(m0 + (t >> 2)) * 1024 + (t & 3) * 8;
  const u16* Ag1 = Ag0 + (size_t)64 * 1024;
  const u16* Bg0 = Bt + (size_t)(n0 + (t >> 2)) * 1024 + (t & 3) * 8;

  f32x4 acc[4][2];
#pragma unroll
  for (int mt = 0; mt < 4; mt++)
#pragma unroll
    for (int nt = 0; nt < 2; nt++) acc[mt][nt] = (f32x4){0.f, 0.f, 0.f, 0.f};

  for (int kt = 0; kt < 1024; kt += 32) {
    gll16(Ag0 + kt, As + w * 512);
    gll16(Ag1 + kt, As + 2048 + w * 512);
    gll16(Bg0 + kt, Bs + w * 512);
    __syncthreads();
    short8 af[4], bfr[2];
#pragma unroll
    for (int mt = 0; mt < 4; mt++)
      af[mt] = *(const short8*)&As[(wm * 64 + mt * 16 + lr) * 32 + qd * 8];
#pragma unroll
    for (int nt = 0; nt < 2; nt++)
      bfr[nt] = *(const short8*)&Bs[(wn * 32 + nt * 16 + lr) * 32 + qd * 8];
#pragma unroll
    for (int mt = 0; mt < 4; mt++)
#pragma unroll
      for (int nt = 0; nt < 2; nt++)
        acc[mt][nt] = mfma16(af[mt], bfr[nt], acc[mt][nt]);
    __syncthreads();
  }

#pragma unroll
  for (int mt = 0; mt < 4; mt++)
#pragma unroll
    for (int nt = 0; nt < 2; nt++)
#pragma unroll
      for (int r = 0; r < 4; r++) {
        const int row = m0 + wm * 64 + mt * 16 + qd * 4 + r;
        const int col = n0 + wn * 32 + nt * 16 + lr;
        float v = acc[mt][nt][r] + bf2f(resid[(size_t)maprow_hidden(row) * 1024 + col]);
        Cf[(size_t)row * 1024 + col] = v;
      }
}

// ---------------- attention v6: split-K 2-way, pos from global, 3 blocks/CU ----------------
// grid 1024 flat, LPT order: e<512 -> s=0 (keys [0,1024), 16 tiles, never masked);
// e>=512 -> s=1 (keys [1024,jmax), qt+1 tiles, descending qt). Partial accO (bf16,
// unnormalized) + partial lsum (f32) out; trivial merge since softmax is max-free.
__global__ __launch_bounds__(256, 3) void attn_kernel(
    const u16* __restrict__ qb, const u16* __restrict__ kb,
    const u16* __restrict__ vbT, const u16* __restrict__ posb,
    u16* __restrict__ abp, float* __restrict__ lp) {
  __shared__ __align__(16) u16 Ks[2][64 * 64];   // 16 KB (Ks[1] aliases Q pre-loop)
  __shared__ __align__(16) u16 Vt[2][64 * 64];   // 16 KB  [dh][key]
  __shared__ __align__(16) u16 Pt[4][16 * 68];   // 8.5 KB wave-private P tiles

  const int t = threadIdx.x;
  const int lane = t & 63, w = t >> 6;
  const int qd = lane >> 4, lr = lane & 15;

  int s, qt, h, b;
  const int e = blockIdx.x;
  if (e < 512) { s = 0; qt = e & 15; h = (e >> 4) & 15; b = e >> 8; }
  else { const int e2 = e - 512; s = 1; qt = 15 - (e2 >> 5); h = e2 & 15; b = (e2 >> 4) & 1; }
  const int i0 = qt * 64;
  const int k0 = s << 10;
  const int k1 = s ? min(K_, i0 + 64 + M_) : 1024;

  const int swz = ((t & 7) ^ ((t >> 3) & 7)) * 8;
  const int c0 = (qd ^ (lr & 7)) * 8;
  const int c1 = c0 ^ 32;
  const int row8 = t >> 3;
  const int bw0 = 48 - w * 16;

  // ---- initial staging: Q -> Ks[1], K/V tile k0 -> buf0 ----
#pragma unroll
  for (int rd = 0; rd < 2; rd++) {
    gll16(qb + (size_t)(b * S_ + i0 + rd * 32 + row8) * 1024 + h * 64 + swz,
          &Ks[1][0] + rd * 2048 + w * 512);
    gll16(kb + (size_t)(b * K_ + k0 + rd * 32 + row8) * 1024 + h * 64 + swz,
          &Ks[0][0] + rd * 2048 + w * 512);
    gll16(vbT + (size_t)((b * H_ + h) * 64 + rd * 32 + row8) * K_ + k0 + swz,
          &Vt[0][0] + rd * 2048 + w * 512);
  }
  __syncthreads();
  const short8 aQ0 = *(const short8*)&Ks[1][(w * 16 + lr) * 64 + c0];
  const short8 aQ1 = *(const short8*)&Ks[1][(w * 16 + lr) * 64 + c1];

  f32x4 accO[4];
#pragma unroll
  for (int d = 0; d < 4; d++) accO[d] = (f32x4){0.f, 0.f, 0.f, 0.f};
  float lsum[4];
#pragma unroll
  for (int r = 0; r < 4; r++) lsum[r] = 0.f;

  int cur = 0;
  for (int j0 = k0; j0 < k1; j0 += 64) {
    // ---- pos B-frags from global (issued pre-barrier; latency folds into drain) ----
    short8 bP0[5], bP1[5];
#pragma unroll
    for (int pc = 0; pc < 5; pc++) {
      const int prow = 960 - i0 + j0 + bw0 + pc * 16 + lr;
      const u16* pp = posb + ((size_t)b * R_ + prow) * 64 + qd * 8;
      bP0[pc] = *(const short8*)pp;
      bP1[pc] = *(const short8*)(pp + 32);
    }
    __syncthreads();  // drains prev prefetch + pos loads; LDS reuse safe

    // ---- prefetch next-tile K/V ----
    if (j0 + 64 < k1) {
      const int nxt = cur ^ 1;
#pragma unroll
      for (int rd = 0; rd < 2; rd++) {
        gll16(kb + (size_t)(b * K_ + j0 + 64 + rd * 32 + row8) * 1024 + h * 64 + swz,
              &Ks[nxt][0] + rd * 2048 + w * 512);
        gll16(vbT + (size_t)((b * H_ + h) * 64 + rd * 32 + row8) * K_ + j0 + 64 + swz,
              &Vt[nxt][0] + rd * 2048 + w * 512);
      }
    }

    // ---- QK^T ----
    f32x4 sqk[4];
#pragma unroll
    for (int kc = 0; kc < 4; kc++) {
      const short8 bK0 = *(const short8*)&Ks[cur][(kc * 16 + lr) * 64 + c0];
      const short8 bK1 = *(const short8*)&Ks[cur][(kc * 16 + lr) * 64 + c1];
      f32x4 z = {0.f, 0.f, 0.f, 0.f};
      z = mfma16(aQ0, bK0, z);
      sqk[kc] = mfma16(aQ1, bK1, z);
    }
    // ---- Q @ pos-band^T (from registers) ----
    f32x4 zp[5];
#pragma unroll
    for (int pc = 0; pc < 5; pc++) {
      f32x4 z = {0.f, 0.f, 0.f, 0.f};
      z = mfma16(aQ0, bP0[pc], z);
      zp[pc] = mfma16(aQ1, bP1[pc], z);
    }

    // ---- shuffle-based skew gather + max-free softmax ----
    const bool tail = (j0 + 63 > i0 + w * 16 + M_);  // wave-uniform; false for s=0
    float p[4][4];
#pragma unroll
    for (int r = 0; r < 4; r++) {
      const int iL = qd * 4 + r;
      const int d = 15 + lr - iL;
      const int srcl = qd * 16 + (d & 15);
      const bool hi = (d >> 4) & 1;
      float g0 = __shfl(zp[0][r], srcl, 64);
      float g1 = __shfl(zp[1][r], srcl, 64);
      float g2 = __shfl(zp[2][r], srcl, 64);
      float g3 = __shfl(zp[3][r], srcl, 64);
      float g4 = __shfl(zp[4][r], srcl, 64);
      float s0 = sqk[0][r] + (hi ? g1 : g0);
      float s1 = sqk[1][r] + (hi ? g2 : g1);
      float s2 = sqk[2][r] + (hi ? g3 : g2);
      float s3 = sqk[3][r] + (hi ? g4 : g3);
      if (tail) {
        const int key = j0 + lr, lim = i0 + w * 16 + iL + M_;
        if (key      > lim) s0 = NEG_BIG;
        if (key + 16 > lim) s1 = NEG_BIG;
        if (key + 32 > lim) s2 = NEG_BIG;
        if (key + 48 > lim) s3 = NEG_BIG;
      }
      p[0][r] = __expf(s0);
      p[1][r] = __expf(s1);
      p[2][r] = __expf(s2);
      p[3][r] = __expf(s3);
      lsum[r] += p[0][r] + p[1][r] + p[2][r] + p[3][r];
    }

    // ---- P -> wave-private LDS (padded stride 68) -> A-fragments ----
#pragma unroll
    for (int r = 0; r < 4; r++) {
      const int base = (qd * 4 + r) * 68 + lr;
      Pt[w][base +  0] = f2bf(p[0][r]);
      Pt[w][base + 16] = f2bf(p[1][r]);
      Pt[w][base + 32] = f2bf(p[2][r]);
      Pt[w][base + 48] = f2bf(p[3][r]);
    }
    __asm__ volatile("s_waitcnt lgkmcnt(0)" ::: "memory");
    const short8 aP0 = *(const short8*)&Pt[w][lr * 68 + qd * 8];
    const short8 aP1 = *(const short8*)&Pt[w][lr * 68 + 32 + qd * 8];

    // ---- P @ V ----
#pragma unroll
    for (int d2 = 0; d2 < 4; d2++) {
      const short8 bV0 = *(const short8*)&Vt[cur][(d2 * 16 + lr) * 64 + c0];
      const short8 bV1 = *(const short8*)&Vt[cur][(d2 * 16 + lr) * 64 + c1];
      accO[d2] = mfma16(aP0, bV0, accO[d2]);
      accO[d2] = mfma16(aP1, bV1, accO[d2]);
    }
    cur ^= 1;
  }

  // ---- epilogue: partial lsum (16-lane reduce) + unnormalized bf16 accO ----
#pragma unroll
  for (int r = 0; r < 4; r++) {
#pragma unroll
    for (int msk = 1; msk < 16; msk <<= 1) lsum[r] += __shfl_xor(lsum[r], msk, 64);
    const int iG = i0 + w * 16 + qd * 4 + r;
    if (lr == 0) lp[(((s << 1) + b) * 16 + h) * 1024 + iG] = lsum[r];
  }
#pragma unroll
  for (int d2 = 0; d2 < 4; d2++)
#pragma unroll
    for (int r = 0; r < 4; r++) {
      const int iG = i0 + w * 16 + qd * 4 + r;
      abp[(size_t)(((s << 1) + b) * S_ + iG) * 1024 + h * 64 + d2 * 16 + lr] =
          f2bf(accO[d2][r]);
    }
}

// ---------------- merge: O = (a0+a1)/(l0+l1), bf16 out ----------------
__global__ __launch_bounds__(256) void merge_kernel(
    const u16* __restrict__ abp, const float* __restrict__ lp,
    u16* __restrict__ ab) {
  const int rowg = blockIdx.x;           // b*S + row
  const int b = rowg >> 10, row = rowg & 1023;
  const int t = threadIdx.x;
  const int c = t * 4;
  const int h = t >> 4;
  const float l0 = lp[(b * 16 + h) * 1024 + row];
  const float l1 = lp[((2 + b) * 16 + h) * 1024 + row];
  const float inv = 1.0f / (l0 + l1);
  ushort4 a0 = *(const ushort4*)&abp[((size_t)(b * S_ + row)) * 1024 + c];
  ushort4 a1 = *(const ushort4*)&abp[((size_t)((2 + b) * S_ + row)) * 1024 + c];
  ushort4 o;
  o.x = f2bf((bf2f(a0.x) + bf2f(a1.x)) * inv);
  o.y = f2bf((bf2f(a0.y) + bf2f(a1.y)) * inv);
  o.z = f2bf((bf2f(a0.z) + bf2f(a1.z)) * inv);
  o.w = f2bf((bf2f(a0.w) + bf2f(a1.w)) * inv);
  *(ushort4*)&ab[((size_t)(b * S_ + row)) * 1024 + c] = o;
}

// ---------------- launch ----------------
extern "C" void kernel_launch(void* const* d_in, const int* in_sizes, int n_in,
                              void* d_out, int out_size, void* d_ws, size_t ws_size,
                              hipStream_t stream) {
  const float* hidden = (const float*)d_in[0];
  const float* pos    = (const float*)d_in[1];
  const float* memory = (const float*)d_in[2];
  // d_in[3] = mask (bool) — causality applied analytically, unused
  const float* Wq = (const float*)d_in[4];
  const float* Wk = (const float*)d_in[5];
  const float* Wv = (const float*)d_in[6];
  const float* Wo = (const float*)d_in[7];
  const float* gamma = (const float*)d_in[8];
  const float* beta  = (const float*)d_in[9];

  char* ws = (char*)d_ws;
  u16* cln  = (u16*)(ws);               // 8 MB
  u16* qb   = (u16*)(ws + 8388608);     // 4 MB (pre-scaled 1/32)
  u16* kb   = (u16*)(ws + 12582912);    // 8 MB
  u16* vbT  = (u16*)(ws + 20971520);    // 8 MB
  u16* ab   = (u16*)(ws + 29360128);    // 4 MB
  u16* WoT  = (u16*)(ws + 33554432);    // 2 MB (kept through out GEMM)
  u16* WqT  = (u16*)(ws + 35651584);    // 3 x 2 MB contiguous Wq|Wk|Wv (dead after QKV)
  u16* WkT  = WqT + 1048576;
  u16* WvT  = WkT + 1048576;
  u16* abp  = (u16*)(ws + 35651584);    // 8 MB partials — OVERLAYS WqT/WkT/WvT
  float* lp = (float*)(ws + 45088768);  // 256 KB partial lsums
  u16* posb = (u16*)(ws + 44040192);    // ~1 MB

  prep_kernel<<<dim3(5632), 256, 0, stream>>>(
      hidden, memory, gamma, beta, cln,
      Wq, Wk, Wv, Wo, WqT, WkT, WvT, WoT, pos, posb);
  gemm_qkv_kernel<<<dim3(24, 32), 256, 0, stream>>>(cln, WqT, qb, kb, vbT);
  attn_kernel<<<dim3(1024), 256, 0, stream>>>(qb, kb, vbT, posb, abp, lp);
  merge_kernel<<<dim3(B_ * S_), 256, 0, stream>>>(abp, lp, ab);
  out_gemm_kernel<<<dim3(16, 16), 256, 0, stream>>>(ab, WoT, cln, (float*)d_out);
}

// Round 12
// 216.936 us; speedup vs baseline: 1.0554x; 1.0554x over previous
//
#include <hip/hip_runtime.h>
#include <hip/hip_bf16.h>

// Problem constants (B,S,M,D,H,DH = 2,1024,1024,1024,16,64)
#define B_ 2
#define S_ 1024
#define M_ 1024
#define D_ 1024
#define H_ 16
#define DH_ 64
#define K_ 2048
#define R_ 4095

// finite stand-in for -inf (avoids inf arithmetic under fast-math)
#define NEG_BIG (-1e30f)

typedef unsigned short u16;
typedef short short8 __attribute__((ext_vector_type(8)));
typedef float f32x4 __attribute__((ext_vector_type(4)));

__device__ __forceinline__ u16 f2bf(float f) {
  __hip_bfloat16 h = __float2bfloat16(f);
  return *reinterpret_cast<u16*>(&h);
}
__device__ __forceinline__ float bf2f(u16 u) {
  __hip_bfloat16 h;
  *reinterpret_cast<u16*>(&h) = u;
  return __bfloat162float(h);
}

// async global->LDS, 16B per lane; LDS dest = wave-uniform base + lane*16
__device__ __forceinline__ void gll16(const void* g, const void* l) {
  __builtin_amdgcn_global_load_lds(
      (const __attribute__((address_space(1))) unsigned int*)g,
      (__attribute__((address_space(3))) unsigned int*)l, 16, 0, 0);
}

__device__ __forceinline__ f32x4 mfma16(short8 a, short8 b, f32x4 c) {
  return __builtin_amdgcn_mfma_f32_16x16x32_bf16(a, b, c, 0, 0, 0);
}

// ---------------- fused prep: LN(concat) + 4x weight transpose + pos cvt ----------------
__global__ __launch_bounds__(256) void prep_kernel(
    const float* __restrict__ hidden, const float* __restrict__ memory,
    const float* __restrict__ gamma, const float* __restrict__ beta,
    u16* __restrict__ cln,
    const float* __restrict__ W0, const float* __restrict__ W1,
    const float* __restrict__ W2, const float* __restrict__ W3,
    u16* __restrict__ O0, u16* __restrict__ O1,
    u16* __restrict__ O2, u16* __restrict__ O3,
    const float* __restrict__ pos, u16* __restrict__ posb) {
  __shared__ u16 tile[64][66];
  __shared__ float red[8];
  const int bx = blockIdx.x;
  const int t = threadIdx.x;

  if (bx < 4096) {  // LayerNorm row
    const int b = bx >> 11;
    const int idx = bx & (K_ - 1);
    const float* src = (idx < M_)
        ? memory + (size_t)(b * M_ + idx) * D_
        : hidden + (size_t)(b * S_ + (idx - M_)) * D_;
    const int lane = t & 63, w = t >> 6;
    float4 rv = ((const float4*)src)[t];
    float s = rv.x + rv.y + rv.z + rv.w;
    float ss = rv.x * rv.x + rv.y * rv.y + rv.z * rv.z + rv.w * rv.w;
#pragma unroll
    for (int m = 1; m < 64; m <<= 1) {
      s += __shfl_xor(s, m, 64);
      ss += __shfl_xor(ss, m, 64);
    }
    if (lane == 0) { red[w] = s; red[4 + w] = ss; }
    __syncthreads();
    s = red[0] + red[1] + red[2] + red[3];
    ss = red[4] + red[5] + red[6] + red[7];
    const float mu = s * (1.0f / D_);
    const float var = ss * (1.0f / D_) - mu * mu;
    const float rstd = rsqrtf(var + 1e-5f);
    float4 gv = ((const float4*)gamma)[t];
    float4 bv = ((const float4*)beta)[t];
    ushort4 ov;
    ov.x = f2bf((rv.x - mu) * rstd * gv.x + bv.x);
    ov.y = f2bf((rv.y - mu) * rstd * gv.y + bv.y);
    ov.z = f2bf((rv.z - mu) * rstd * gv.z + bv.z);
    ov.w = f2bf((rv.w - mu) * rstd * gv.w + bv.w);
    ((ushort4*)(cln + (size_t)bx * D_))[t] = ov;
    return;
  }
  if (bx < 5120) {  // weight transpose slab
    const int z = (bx - 4096) >> 8;
    const int rem = (bx - 4096) & 255;
    const float* in; u16* out;
    switch (z) {
      case 0:  in = W0; out = O0; break;
      case 1:  in = W1; out = O1; break;
      case 2:  in = W2; out = O2; break;
      default: in = W3; out = O3; break;
    }
    const int tx = t & 63, ty = t >> 6;
    const int k0 = (rem & 15) * 64, n0 = (rem >> 4) * 64;
#pragma unroll
    for (int i = ty; i < 64; i += 4)
      tile[i][tx] = f2bf(in[(size_t)(k0 + i) * D_ + n0 + tx]);
    __syncthreads();
#pragma unroll
    for (int i = ty; i < 64; i += 4)
      out[(size_t)(n0 + i) * D_ + k0 + tx] = tile[tx][i];
    return;
  }
  // pos f32 -> bf16
  const int i = (bx - 5120) * 256 + t;
  const int n4 = B_ * R_ * 64 / 4;
  if (i < n4) {
    float4 v = ((const float4*)pos)[i];
    ushort4 o;
    o.x = f2bf(v.x); o.y = f2bf(v.y); o.z = f2bf(v.z); o.w = f2bf(v.w);
    ((ushort4*)posb)[i] = o;
  }
}

// row r of the "hidden slice" view -> row of c_ln
__device__ __forceinline__ int maprow_hidden(int r) {
  return r + ((r >> 10) << 10) + M_;
}

// ---------------- QKV GEMM: BK=64, XOR-swizzled staging, 16 barrier-pairs ----------------
__global__ __launch_bounds__(256, 2) void gemm_qkv_kernel(
    const u16* __restrict__ A, const u16* __restrict__ Bt,
    u16* __restrict__ qb, u16* __restrict__ kb, u16* __restrict__ vbT) {
  __shared__ __align__(16) u16 As[128 * 64];   // 16 KB
  __shared__ __align__(16) u16 Bs[128 * 64];   // 16 KB
  const int t = threadIdx.x;
  const int lane = t & 63, w = t >> 6;
  const int wm = w >> 1, wn = w & 1;
  const int qd = lane >> 4, lr = lane & 15;
  const int m0 = blockIdx.y * 128, n0 = blockIdx.x * 128;
  if (n0 < 1024 && !(m0 & 1024)) return;   // dead Q tiles (memory rows)

  const int swz = ((t & 7) ^ ((t >> 3) & 7)) * 8;  // source-chunk swizzle
  const int c0 = (qd ^ (lr & 7)) * 8;
  const int c1 = c0 ^ 32;
  const int row8 = (t >> 3) & 7;

  f32x4 acc[4][4];
#pragma unroll
  for (int mt = 0; mt < 4; mt++)
#pragma unroll
    for (int nt = 0; nt < 4; nt++) acc[mt][nt] = (f32x4){0.f, 0.f, 0.f, 0.f};

  for (int kt = 0; kt < 1024; kt += 64) {
#pragma unroll
    for (int p = 0; p < 4; p++) {
      const int ra = w * 32 + p * 8 + row8;
      gll16(A + (size_t)(m0 + ra) * 1024 + kt + swz, As + (w * 32 + p * 8) * 64);
      gll16(Bt + (size_t)(n0 + ra) * 1024 + kt + swz, Bs + (w * 32 + p * 8) * 64);
    }
    __syncthreads();
    short8 a0[4], a1[4], b0[4], b1[4];
#pragma unroll
    for (int mt = 0; mt < 4; mt++) {
      a0[mt] = *(const short8*)&As[(wm * 64 + mt * 16 + lr) * 64 + c0];
      a1[mt] = *(const short8*)&As[(wm * 64 + mt * 16 + lr) * 64 + c1];
    }
#pragma unroll
    for (int nt = 0; nt < 4; nt++) {
      b0[nt] = *(const short8*)&Bs[(wn * 64 + nt * 16 + lr) * 64 + c0];
      b1[nt] = *(const short8*)&Bs[(wn * 64 + nt * 16 + lr) * 64 + c1];
    }
#pragma unroll
    for (int mt = 0; mt < 4; mt++)
#pragma unroll
      for (int nt = 0; nt < 4; nt++) {
        acc[mt][nt] = mfma16(a0[mt], b0[nt], acc[mt][nt]);
        acc[mt][nt] = mfma16(a1[mt], b1[nt], acc[mt][nt]);
      }
    __syncthreads();
  }

#pragma unroll
  for (int mt = 0; mt < 4; mt++)
#pragma unroll
    for (int nt = 0; nt < 4; nt++) {
      const int colb = n0 + wn * 64 + nt * 16;
      const int rowb = m0 + wm * 64 + mt * 16 + qd * 4;
      if (colb < 1024) {                               // Q (pre-scaled 1/32)
        const int qrow = ((rowb >> 11) << 10) | (rowb & 1023);
#pragma unroll
        for (int r = 0; r < 4; r++)
          qb[(size_t)(qrow + r) * 1024 + colb + lr] = f2bf(acc[mt][nt][r] * 0.03125f);
      } else if (colb < 2048) {                        // K row-major
        const int key = rowb & (K_ - 1);
        const int bq = rowb >> 11;
#pragma unroll
        for (int r = 0; r < 4; r++)
          kb[(size_t)(bq * K_ + key + r) * 1024 + (colb - 1024) + lr] = f2bf(acc[mt][nt][r]);
      } else {                                         // V transposed [b*H+h][dh][key]
        const int nn = colb - 2048 + lr;
        const int bh = ((rowb >> 11) << 4) | (nn >> 6);
        const int dh = nn & 63;
        const int key = rowb & (K_ - 1);
        ushort4 pk;
        pk.x = f2bf(acc[mt][nt][0]);
        pk.y = f2bf(acc[mt][nt][1]);
        pk.z = f2bf(acc[mt][nt][2]);
        pk.w = f2bf(acc[mt][nt][3]);
        *(ushort4*)&vbT[((size_t)bh * 64 + dh) * K_ + key] = pk;
      }
    }
}

// ---------------- out GEMM: 128x64 tiles (256 blocks), f32 out + LN residual ----------------
__global__ __launch_bounds__(256, 2) void out_gemm_kernel(
    const u16* __restrict__ A, const u16* __restrict__ Bt,
    const u16* __restrict__ resid, float* __restrict__ Cf) {
  __shared__ __align__(16) u16 As[128 * 32];
  __shared__ __align__(16) u16 Bs[64 * 32];
  const int t = threadIdx.x;
  const int lane = t & 63, w = t >> 6;
  const int wm = w >> 1, wn = w & 1;
  const int qd = lane >> 4, lr = lane & 15;
  const int m0 = blockIdx.y * 128, n0 = blockIdx.x * 64;

  const u16* Ag0 = A + (size_t)(m0 + (t >> 2)) * 1024 + (t & 3) * 8;
  const u16* Ag1 = Ag0 + (size_t)64 * 1024;
  const u16* Bg0 = Bt + (size_t)(n0 + (t >> 2)) * 1024 + (t & 3) * 8;

  f32x4 acc[4][2];
#pragma unroll
  for (int mt = 0; mt < 4; mt++)
#pragma unroll
    for (int nt = 0; nt < 2; nt++) acc[mt][nt] = (f32x4){0.f, 0.f, 0.f, 0.f};

  for (int kt = 0; kt < 1024; kt += 32) {
    gll16(Ag0 + kt, As + w * 512);
    gll16(Ag1 + kt, As + 2048 + w * 512);
    gll16(Bg0 + kt, Bs + w * 512);
    __syncthreads();
    short8 af[4], bfr[2];
#pragma unroll
    for (int mt = 0; mt < 4; mt++)
      af[mt] = *(const short8*)&As[(wm * 64 + mt * 16 + lr) * 32 + qd * 8];
#pragma unroll
    for (int nt = 0; nt < 2; nt++)
      bfr[nt] = *(const short8*)&Bs[(wn * 32 + nt * 16 + lr) * 32 + qd * 8];
#pragma unroll
    for (int mt = 0; mt < 4; mt++)
#pragma unroll
      for (int nt = 0; nt < 2; nt++)
        acc[mt][nt] = mfma16(af[mt], bfr[nt], acc[mt][nt]);
    __syncthreads();
  }

#pragma unroll
  for (int mt = 0; mt < 4; mt++)
#pragma unroll
    for (int nt = 0; nt < 2; nt++)
#pragma unroll
      for (int r = 0; r < 4; r++) {
        const int row = m0 + wm * 64 + mt * 16 + qd * 4 + r;
        const int col = n0 + wn * 32 + nt * 16 + lr;
        float v = acc[mt][nt][r] + bf2f(resid[(size_t)maprow_hidden(row) * 1024 + col]);
        Cf[(size_t)row * 1024 + col] = v;
      }
}

// ---------------- attention (R10-proven): max-free softmax, Ps rolling LDS window, ------
// K/V double-buffered, ONE barrier per tile, balance flip. grid (16, H, B).
__global__ __launch_bounds__(256, 2) void attn_kernel(
    const u16* __restrict__ qb, const u16* __restrict__ kb,
    const u16* __restrict__ vbT, const u16* __restrict__ pos,
    u16* __restrict__ ab) {
  __shared__ __align__(16) u16 Ks[2][64 * 64];   // 16 KB (Ks[1] aliases Q pre-loop)
  __shared__ __align__(16) u16 Vt[2][64 * 64];   // 16 KB  [dh][key]
  __shared__ __align__(16) u16 Ps[192 * 64];     // 24 KB  rolling pos window
  __shared__ __align__(16) u16 Pt[4][16 * 68];   // 8.5 KB wave-private P tiles

  const int t = threadIdx.x;
  const int lane = t & 63, w = t >> 6;
  const int qd = lane >> 4, lr = lane & 15;
  const int h = blockIdx.y;
  const int b = blockIdx.z;
  int qt = blockIdx.x;
  if (b) qt = 15 - qt;                // load-balance flip
  const int i0 = qt * 64;

  const int swz = ((t & 7) ^ ((t >> 3) & 7)) * 8;  // staging source-chunk swizzle
  const int c0 = (qd ^ (lr & 7)) * 8;              // fragment-read chunk offsets
  const int c1 = c0 ^ 32;
  const int base0 = 960 - i0;                      // pos band origin (>= 0)
  const int row8 = t >> 3;

  // ---- pre-loop staging: Q -> Ks[1], tile0 K/V -> buf0, pos rows [0,128) ----
#pragma unroll
  for (int rd = 0; rd < 2; rd++)
    gll16(qb + (size_t)(b * S_ + i0 + rd * 32 + row8) * 1024 + h * 64 + swz,
          &Ks[1][0] + rd * 2048 + w * 512);
#pragma unroll
  for (int rd = 0; rd < 2; rd++) {
    gll16(kb + (size_t)(b * K_ + rd * 32 + row8) * 1024 + h * 64 + swz,
          &Ks[0][0] + rd * 2048 + w * 512);
    gll16(vbT + (size_t)((b * H_ + h) * 64 + rd * 32 + row8) * K_ + swz,
          &Vt[0][0] + rd * 2048 + w * 512);
  }
#pragma unroll
  for (int rd = 0; rd < 4; rd++)
    gll16(pos + (size_t)(b * R_ + base0 + rd * 32 + row8) * 64 + swz,
          Ps + rd * 2048 + w * 512);
  __syncthreads();
  const short8 aQ0 = *(const short8*)&Ks[1][(w * 16 + lr) * 64 + c0];
  const short8 aQ1 = *(const short8*)&Ks[1][(w * 16 + lr) * 64 + c1];

  f32x4 accO[4];
#pragma unroll
  for (int d = 0; d < 4; d++) accO[d] = (f32x4){0.f, 0.f, 0.f, 0.f};
  float lsum[4];
#pragma unroll
  for (int r = 0; r < 4; r++) lsum[r] = 0.f;

  const int bw0 = 48 - w * 16;
  const int jmax = min(K_, i0 + 64 + M_);
  int sa = 0, sb = 1, sc = 2;   // pos slab rotation
  int cur = 0;

  for (int j0 = 0, tt = 0; j0 < jmax; j0 += 64, tt++) {
    __syncthreads();
    if (j0 + 64 < jmax) {
      const int nxt = cur ^ 1;
#pragma unroll
      for (int rd = 0; rd < 2; rd++) {
        gll16(kb + (size_t)(b * K_ + j0 + 64 + rd * 32 + row8) * 1024 + h * 64 + swz,
              &Ks[nxt][0] + rd * 2048 + w * 512);
        gll16(vbT + (size_t)((b * H_ + h) * 64 + rd * 32 + row8) * K_ + j0 + 64 + swz,
              &Vt[nxt][0] + rd * 2048 + w * 512);
      }
    }
#pragma unroll
    for (int rd = 0; rd < 2; rd++)
      gll16(pos + (size_t)(b * R_ + base0 + 64 * tt + 128 + rd * 32 + row8) * 64 + swz,
            Ps + (sc * 64 + rd * 32) * 64 + w * 512);

    // ---- QK^T: 16 rows x 64 keys ----
    f32x4 sqk[4];
#pragma unroll
    for (int kc = 0; kc < 4; kc++) {
      const short8 bK0 = *(const short8*)&Ks[cur][(kc * 16 + lr) * 64 + c0];
      const short8 bK1 = *(const short8*)&Ks[cur][(kc * 16 + lr) * 64 + c1];
      f32x4 z = {0.f, 0.f, 0.f, 0.f};
      z = mfma16(aQ0, bK0, z);
      sqk[kc] = mfma16(aQ1, bK1, z);
    }
    // ---- Q @ pos-band^T: 16 rows x 80 band cols, kept in registers ----
    f32x4 zp[5];
#pragma unroll
    for (int pc = 0; pc < 5; pc++) {
      const int xb = bw0 + pc * 16;
      const int slab = (xb >= 64) ? sb : sa;
      const int pb = slab * 64 + (xb & 63);
      const short8 bP0 = *(const short8*)&Ps[(pb + lr) * 64 + c0];
      const short8 bP1 = *(const short8*)&Ps[(pb + lr) * 64 + c1];
      f32x4 z = {0.f, 0.f, 0.f, 0.f};
      z = mfma16(aQ0, bP0, z);
      zp[pc] = mfma16(aQ1, bP1, z);
    }

    // ---- shuffle-based skew gather + max-free softmax ----
    const bool tail = (j0 + 63 > i0 + w * 16 + M_);  // wave-uniform
    float p[4][4];
#pragma unroll
    for (int r = 0; r < 4; r++) {
      const int iL = qd * 4 + r;
      const int d = 15 + lr - iL;                    // [0,30]
      const int srcl = qd * 16 + (d & 15);
      const bool hi = (d >> 4) & 1;
      float g0 = __shfl(zp[0][r], srcl, 64);
      float g1 = __shfl(zp[1][r], srcl, 64);
      float g2 = __shfl(zp[2][r], srcl, 64);
      float g3 = __shfl(zp[3][r], srcl, 64);
      float g4 = __shfl(zp[4][r], srcl, 64);
      float s0 = sqk[0][r] + (hi ? g1 : g0);
      float s1 = sqk[1][r] + (hi ? g2 : g1);
      float s2 = sqk[2][r] + (hi ? g3 : g2);
      float s3 = sqk[3][r] + (hi ? g4 : g3);
      if (tail) {
        const int key = j0 + lr, lim = i0 + w * 16 + iL + M_;
        if (key      > lim) s0 = NEG_BIG;
        if (key + 16 > lim) s1 = NEG_BIG;
        if (key + 32 > lim) s2 = NEG_BIG;
        if (key + 48 > lim) s3 = NEG_BIG;
      }
      p[0][r] = __expf(s0);
      p[1][r] = __expf(s1);
      p[2][r] = __expf(s2);
      p[3][r] = __expf(s3);
      lsum[r] += p[0][r] + p[1][r] + p[2][r] + p[3][r];
    }

    // ---- P -> wave-private LDS (padded stride 68) -> A-fragments ----
#pragma unroll
    for (int r = 0; r < 4; r++) {
      const int base = (qd * 4 + r) * 68 + lr;
      Pt[w][base +  0] = f2bf(p[0][r]);
      Pt[w][base + 16] = f2bf(p[1][r]);
      Pt[w][base + 32] = f2bf(p[2][r]);
      Pt[w][base + 48] = f2bf(p[3][r]);
    }
    __asm__ volatile("s_waitcnt lgkmcnt(0)" ::: "memory");
    const short8 aP0 = *(const short8*)&Pt[w][lr * 68 + qd * 8];
    const short8 aP1 = *(const short8*)&Pt[w][lr * 68 + 32 + qd * 8];

    // ---- P @ V ----
#pragma unroll
    for (int d2 = 0; d2 < 4; d2++) {
      const short8 bV0 = *(const short8*)&Vt[cur][(d2 * 16 + lr) * 64 + c0];
      const short8 bV1 = *(const short8*)&Vt[cur][(d2 * 16 + lr) * 64 + c1];
      accO[d2] = mfma16(aP0, bV0, accO[d2]);
      accO[d2] = mfma16(aP1, bV1, accO[d2]);
    }

    const int so = sa; sa = sb; sb = sc; sc = so;
    cur ^= 1;
  }

  // ---- epilogue: one 16-lane reduction of lsum, then normalize ----
  float inv[4];
#pragma unroll
  for (int r = 0; r < 4; r++) {
#pragma unroll
    for (int msk = 1; msk < 16; msk <<= 1) lsum[r] += __shfl_xor(lsum[r], msk, 64);
    inv[r] = 1.0f / lsum[r];
  }
#pragma unroll
  for (int d2 = 0; d2 < 4; d2++)
#pragma unroll
    for (int r = 0; r < 4; r++) {
      const int iG = i0 + w * 16 + qd * 4 + r;
      ab[(size_t)(b * S_ + iG) * 1024 + h * 64 + d2 * 16 + lr] = f2bf(accO[d2][r] * inv[r]);
    }
}

// ---------------- launch ----------------
extern "C" void kernel_launch(void* const* d_in, const int* in_sizes, int n_in,
                              void* d_out, int out_size, void* d_ws, size_t ws_size,
                              hipStream_t stream) {
  const float* hidden = (const float*)d_in[0];
  const float* pos    = (const float*)d_in[1];
  const float* memory = (const float*)d_in[2];
  // d_in[3] = mask (bool) — causality applied analytically, unused
  const float* Wq = (const float*)d_in[4];
  const float* Wk = (const float*)d_in[5];
  const float* Wv = (const float*)d_in[6];
  const float* Wo = (const float*)d_in[7];
  const float* gamma = (const float*)d_in[8];
  const float* beta  = (const float*)d_in[9];

  char* ws = (char*)d_ws;
  u16* cln  = (u16*)(ws);               // 8 MB
  u16* qb   = (u16*)(ws + 8388608);     // 4 MB (pre-scaled 1/32)
  u16* kb   = (u16*)(ws + 12582912);    // 8 MB
  u16* vbT  = (u16*)(ws + 20971520);    // 8 MB
  u16* ab   = (u16*)(ws + 29360128);    // 4 MB
  u16* WqT  = (u16*)(ws + 33554432);    // 4 x 2 MB contiguous (WqT|WkT|WvT|WoT)
  u16* WkT  = WqT + 1048576;
  u16* WvT  = WkT + 1048576;
  u16* WoT  = WvT + 1048576;
  u16* posb = (u16*)(ws + 41943040);    // ~1 MB

  prep_kernel<<<dim3(5632), 256, 0, stream>>>(
      hidden, memory, gamma, beta, cln,
      Wq, Wk, Wv, Wo, WqT, WkT, WvT, WoT, pos, posb);
  gemm_qkv_kernel<<<dim3(24, 32), 256, 0, stream>>>(cln, WqT, qb, kb, vbT);
  attn_kernel<<<dim3(S_ / 64, H_, B_), 256, 0, stream>>>(qb, kb, vbT, posb, ab);
  out_gemm_kernel<<<dim3(16, 16), 256, 0, stream>>>(ab, WoT, cln, (float*)d_out);
}

// Round 13
// 210.357 us; speedup vs baseline: 1.0884x; 1.0313x over previous
//
#include <hip/hip_runtime.h>
#include <hip/hip_bf16.h>

// Problem constants (B,S,M,D,H,DH = 2,1024,1024,1024,16,64)
#define B_ 2
#define S_ 1024
#define M_ 1024
#define D_ 1024
#define H_ 16
#define DH_ 64
#define K_ 2048
#define R_ 4095

// finite stand-in for -inf (avoids inf arithmetic under fast-math)
#define NEG_BIG (-1e30f)

typedef unsigned short u16;
typedef short short8 __attribute__((ext_vector_type(8)));
typedef float f32x4 __attribute__((ext_vector_type(4)));

__device__ __forceinline__ u16 f2bf(float f) {
  __hip_bfloat16 h = __float2bfloat16(f);
  return *reinterpret_cast<u16*>(&h);
}
__device__ __forceinline__ float bf2f(u16 u) {
  __hip_bfloat16 h;
  *reinterpret_cast<u16*>(&h) = u;
  return __bfloat162float(h);
}

// async global->LDS, 16B per lane; LDS dest = wave-uniform base + lane*16
__device__ __forceinline__ void gll16(const void* g, const void* l) {
  __builtin_amdgcn_global_load_lds(
      (const __attribute__((address_space(1))) unsigned int*)g,
      (__attribute__((address_space(3))) unsigned int*)l, 16, 0, 0);
}

__device__ __forceinline__ f32x4 mfma16(short8 a, short8 b, f32x4 c) {
  return __builtin_amdgcn_mfma_f32_16x16x32_bf16(a, b, c, 0, 0, 0);
}

// ---------------- fused prep: LN(concat) + 4x weight transpose + pos cvt ----------------
__global__ __launch_bounds__(256) void prep_kernel(
    const float* __restrict__ hidden, const float* __restrict__ memory,
    const float* __restrict__ gamma, const float* __restrict__ beta,
    u16* __restrict__ cln,
    const float* __restrict__ W0, const float* __restrict__ W1,
    const float* __restrict__ W2, const float* __restrict__ W3,
    u16* __restrict__ O0, u16* __restrict__ O1,
    u16* __restrict__ O2, u16* __restrict__ O3,
    const float* __restrict__ pos, u16* __restrict__ posb) {
  __shared__ u16 tile[64][66];
  __shared__ float red[8];
  const int bx = blockIdx.x;
  const int t = threadIdx.x;

  if (bx < 4096) {  // LayerNorm row
    const int b = bx >> 11;
    const int idx = bx & (K_ - 1);
    const float* src = (idx < M_)
        ? memory + (size_t)(b * M_ + idx) * D_
        : hidden + (size_t)(b * S_ + (idx - M_)) * D_;
    const int lane = t & 63, w = t >> 6;
    float4 rv = ((const float4*)src)[t];
    float s = rv.x + rv.y + rv.z + rv.w;
    float ss = rv.x * rv.x + rv.y * rv.y + rv.z * rv.z + rv.w * rv.w;
#pragma unroll
    for (int m = 1; m < 64; m <<= 1) {
      s += __shfl_xor(s, m, 64);
      ss += __shfl_xor(ss, m, 64);
    }
    if (lane == 0) { red[w] = s; red[4 + w] = ss; }
    __syncthreads();
    s = red[0] + red[1] + red[2] + red[3];
    ss = red[4] + red[5] + red[6] + red[7];
    const float mu = s * (1.0f / D_);
    const float var = ss * (1.0f / D_) - mu * mu;
    const float rstd = rsqrtf(var + 1e-5f);
    float4 gv = ((const float4*)gamma)[t];
    float4 bv = ((const float4*)beta)[t];
    ushort4 ov;
    ov.x = f2bf((rv.x - mu) * rstd * gv.x + bv.x);
    ov.y = f2bf((rv.y - mu) * rstd * gv.y + bv.y);
    ov.z = f2bf((rv.z - mu) * rstd * gv.z + bv.z);
    ov.w = f2bf((rv.w - mu) * rstd * gv.w + bv.w);
    ((ushort4*)(cln + (size_t)bx * D_))[t] = ov;
    return;
  }
  if (bx < 5120) {  // weight transpose slab
    const int z = (bx - 4096) >> 8;
    const int rem = (bx - 4096) & 255;
    const float* in; u16* out;
    switch (z) {
      case 0:  in = W0; out = O0; break;
      case 1:  in = W1; out = O1; break;
      case 2:  in = W2; out = O2; break;
      default: in = W3; out = O3; break;
    }
    const int tx = t & 63, ty = t >> 6;
    const int k0 = (rem & 15) * 64, n0 = (rem >> 4) * 64;
#pragma unroll
    for (int i = ty; i < 64; i += 4)
      tile[i][tx] = f2bf(in[(size_t)(k0 + i) * D_ + n0 + tx]);
    __syncthreads();
#pragma unroll
    for (int i = ty; i < 64; i += 4)
      out[(size_t)(n0 + i) * D_ + k0 + tx] = tile[tx][i];
    return;
  }
  // pos f32 -> bf16
  const int i = (bx - 5120) * 256 + t;
  const int n4 = B_ * R_ * 64 / 4;
  if (i < n4) {
    float4 v = ((const float4*)pos)[i];
    ushort4 o;
    o.x = f2bf(v.x); o.y = f2bf(v.y); o.z = f2bf(v.z); o.w = f2bf(v.w);
    ((ushort4*)posb)[i] = o;
  }
}

// row r of the "hidden slice" view -> row of c_ln
__device__ __forceinline__ int maprow_hidden(int r) {
  return r + ((r >> 10) << 10) + M_;
}

// ---------------- QKV GEMM: BK=64, XOR-swizzled staging, 3 blocks/CU ----------------
// 640 live blocks; at 2/CU (512 slots) this runs 2 scheduling rounds with the
// second 25% full. launch_bounds(256,3) -> VGPR<=168 -> 3/CU (768 slots) = 1 round.
__global__ __launch_bounds__(256, 3) void gemm_qkv_kernel(
    const u16* __restrict__ A, const u16* __restrict__ Bt,
    u16* __restrict__ qb, u16* __restrict__ kb, u16* __restrict__ vbT) {
  __shared__ __align__(16) u16 As[128 * 64];   // 16 KB
  __shared__ __align__(16) u16 Bs[128 * 64];   // 16 KB
  const int t = threadIdx.x;
  const int lane = t & 63, w = t >> 6;
  const int wm = w >> 1, wn = w & 1;
  const int qd = lane >> 4, lr = lane & 15;
  const int m0 = blockIdx.y * 128, n0 = blockIdx.x * 128;
  if (n0 < 1024 && !(m0 & 1024)) return;   // dead Q tiles (memory rows)

  const int swz = ((t & 7) ^ ((t >> 3) & 7)) * 8;  // source-chunk swizzle
  const int c0 = (qd ^ (lr & 7)) * 8;
  const int c1 = c0 ^ 32;
  const int row8 = (t >> 3) & 7;

  f32x4 acc[4][4];
#pragma unroll
  for (int mt = 0; mt < 4; mt++)
#pragma unroll
    for (int nt = 0; nt < 4; nt++) acc[mt][nt] = (f32x4){0.f, 0.f, 0.f, 0.f};

  for (int kt = 0; kt < 1024; kt += 64) {
#pragma unroll
    for (int p = 0; p < 4; p++) {
      const int ra = w * 32 + p * 8 + row8;
      gll16(A + (size_t)(m0 + ra) * 1024 + kt + swz, As + (w * 32 + p * 8) * 64);
      gll16(Bt + (size_t)(n0 + ra) * 1024 + kt + swz, Bs + (w * 32 + p * 8) * 64);
    }
    __syncthreads();
    short8 a0[4], a1[4], b0[4], b1[4];
#pragma unroll
    for (int mt = 0; mt < 4; mt++) {
      a0[mt] = *(const short8*)&As[(wm * 64 + mt * 16 + lr) * 64 + c0];
      a1[mt] = *(const short8*)&As[(wm * 64 + mt * 16 + lr) * 64 + c1];
    }
#pragma unroll
    for (int nt = 0; nt < 4; nt++) {
      b0[nt] = *(const short8*)&Bs[(wn * 64 + nt * 16 + lr) * 64 + c0];
      b1[nt] = *(const short8*)&Bs[(wn * 64 + nt * 16 + lr) * 64 + c1];
    }
#pragma unroll
    for (int mt = 0; mt < 4; mt++)
#pragma unroll
      for (int nt = 0; nt < 4; nt++) {
        acc[mt][nt] = mfma16(a0[mt], b0[nt], acc[mt][nt]);
        acc[mt][nt] = mfma16(a1[mt], b1[nt], acc[mt][nt]);
      }
    __syncthreads();
  }

#pragma unroll
  for (int mt = 0; mt < 4; mt++)
#pragma unroll
    for (int nt = 0; nt < 4; nt++) {
      const int colb = n0 + wn * 64 + nt * 16;
      const int rowb = m0 + wm * 64 + mt * 16 + qd * 4;
      if (colb < 1024) {                               // Q (pre-scaled 1/32)
        const int qrow = ((rowb >> 11) << 10) | (rowb & 1023);
#pragma unroll
        for (int r = 0; r < 4; r++)
          qb[(size_t)(qrow + r) * 1024 + colb + lr] = f2bf(acc[mt][nt][r] * 0.03125f);
      } else if (colb < 2048) {                        // K row-major
        const int key = rowb & (K_ - 1);
        const int bq = rowb >> 11;
#pragma unroll
        for (int r = 0; r < 4; r++)
          kb[(size_t)(bq * K_ + key + r) * 1024 + (colb - 1024) + lr] = f2bf(acc[mt][nt][r]);
      } else {                                         // V transposed [b*H+h][dh][key]
        const int nn = colb - 2048 + lr;
        const int bh = ((rowb >> 11) << 4) | (nn >> 6);
        const int dh = nn & 63;
        const int key = rowb & (K_ - 1);
        ushort4 pk;
        pk.x = f2bf(acc[mt][nt][0]);
        pk.y = f2bf(acc[mt][nt][1]);
        pk.z = f2bf(acc[mt][nt][2]);
        pk.w = f2bf(acc[mt][nt][3]);
        *(ushort4*)&vbT[((size_t)bh * 64 + dh) * K_ + key] = pk;
      }
    }
}

// ---------------- out GEMM: 128x64 tiles (256 blocks), f32 out + LN residual ----------------
__global__ __launch_bounds__(256, 2) void out_gemm_kernel(
    const u16* __restrict__ A, const u16* __restrict__ Bt,
    const u16* __restrict__ resid, float* __restrict__ Cf) {
  __shared__ __align__(16) u16 As[128 * 32];
  __shared__ __align__(16) u16 Bs[64 * 32];
  const int t = threadIdx.x;
  const int lane = t & 63, w = t >> 6;
  const int wm = w >> 1, wn = w & 1;
  const int qd = lane >> 4, lr = lane & 15;
  const int m0 = blockIdx.y * 128, n0 = blockIdx.x * 64;

  const u16* Ag0 = A + (size_t)(m0 + (t >> 2)) * 1024 + (t & 3) * 8;
  const u16* Ag1 = Ag0 + (size_t)64 * 1024;
  const u16* Bg0 = Bt + (size_t)(n0 + (t >> 2)) * 1024 + (t & 3) * 8;

  f32x4 acc[4][2];
#pragma unroll
  for (int mt = 0; mt < 4; mt++)
#pragma unroll
    for (int nt = 0; nt < 2; nt++) acc[mt][nt] = (f32x4){0.f, 0.f, 0.f, 0.f};

  for (int kt = 0; kt < 1024; kt += 32) {
    gll16(Ag0 + kt, As + w * 512);
    gll16(Ag1 + kt, As + 2048 + w * 512);
    gll16(Bg0 + kt, Bs + w * 512);
    __syncthreads();
    short8 af[4], bfr[2];
#pragma unroll
    for (int mt = 0; mt < 4; mt++)
      af[mt] = *(const short8*)&As[(wm * 64 + mt * 16 + lr) * 32 + qd * 8];
#pragma unroll
    for (int nt = 0; nt < 2; nt++)
      bfr[nt] = *(const short8*)&Bs[(wn * 32 + nt * 16 + lr) * 32 + qd * 8];
#pragma unroll
    for (int mt = 0; mt < 4; mt++)
#pragma unroll
      for (int nt = 0; nt < 2; nt++)
        acc[mt][nt] = mfma16(af[mt], bfr[nt], acc[mt][nt]);
    __syncthreads();
  }

#pragma unroll
  for (int mt = 0; mt < 4; mt++)
#pragma unroll
    for (int nt = 0; nt < 2; nt++)
#pragma unroll
      for (int r = 0; r < 4; r++) {
        const int row = m0 + wm * 64 + mt * 16 + qd * 4 + r;
        const int col = n0 + wn * 32 + nt * 16 + lr;
        float v = acc[mt][nt][r] + bf2f(resid[(size_t)maprow_hidden(row) * 1024 + col]);
        Cf[(size_t)row * 1024 + col] = v;
      }
}

// ---------------- attention (R10-proven): max-free softmax, Ps rolling LDS window, ------
// K/V double-buffered, ONE barrier per tile, balance flip. grid (16, H, B).
__global__ __launch_bounds__(256, 2) void attn_kernel(
    const u16* __restrict__ qb, const u16* __restrict__ kb,
    const u16* __restrict__ vbT, const u16* __restrict__ pos,
    u16* __restrict__ ab) {
  __shared__ __align__(16) u16 Ks[2][64 * 64];   // 16 KB (Ks[1] aliases Q pre-loop)
  __shared__ __align__(16) u16 Vt[2][64 * 64];   // 16 KB  [dh][key]
  __shared__ __align__(16) u16 Ps[192 * 64];     // 24 KB  rolling pos window
  __shared__ __align__(16) u16 Pt[4][16 * 68];   // 8.5 KB wave-private P tiles

  const int t = threadIdx.x;
  const int lane = t & 63, w = t >> 6;
  const int qd = lane >> 4, lr = lane & 15;
  const int h = blockIdx.y;
  const int b = blockIdx.z;
  int qt = blockIdx.x;
  if (b) qt = 15 - qt;                // load-balance flip
  const int i0 = qt * 64;

  const int swz = ((t & 7) ^ ((t >> 3) & 7)) * 8;  // staging source-chunk swizzle
  const int c0 = (qd ^ (lr & 7)) * 8;              // fragment-read chunk offsets
  const int c1 = c0 ^ 32;
  const int base0 = 960 - i0;                      // pos band origin (>= 0)
  const int row8 = t >> 3;

  // ---- pre-loop staging: Q -> Ks[1], tile0 K/V -> buf0, pos rows [0,128) ----
#pragma unroll
  for (int rd = 0; rd < 2; rd++)
    gll16(qb + (size_t)(b * S_ + i0 + rd * 32 + row8) * 1024 + h * 64 + swz,
          &Ks[1][0] + rd * 2048 + w * 512);
#pragma unroll
  for (int rd = 0; rd < 2; rd++) {
    gll16(kb + (size_t)(b * K_ + rd * 32 + row8) * 1024 + h * 64 + swz,
          &Ks[0][0] + rd * 2048 + w * 512);
    gll16(vbT + (size_t)((b * H_ + h) * 64 + rd * 32 + row8) * K_ + swz,
          &Vt[0][0] + rd * 2048 + w * 512);
  }
#pragma unroll
  for (int rd = 0; rd < 4; rd++)
    gll16(pos + (size_t)(b * R_ + base0 + rd * 32 + row8) * 64 + swz,
          Ps + rd * 2048 + w * 512);
  __syncthreads();
  const short8 aQ0 = *(const short8*)&Ks[1][(w * 16 + lr) * 64 + c0];
  const short8 aQ1 = *(const short8*)&Ks[1][(w * 16 + lr) * 64 + c1];

  f32x4 accO[4];
#pragma unroll
  for (int d = 0; d < 4; d++) accO[d] = (f32x4){0.f, 0.f, 0.f, 0.f};
  float lsum[4];
#pragma unroll
  for (int r = 0; r < 4; r++) lsum[r] = 0.f;

  const int bw0 = 48 - w * 16;
  const int jmax = min(K_, i0 + 64 + M_);
  int sa = 0, sb = 1, sc = 2;   // pos slab rotation
  int cur = 0;

  for (int j0 = 0, tt = 0; j0 < jmax; j0 += 64, tt++) {
    __syncthreads();
    if (j0 + 64 < jmax) {
      const int nxt = cur ^ 1;
#pragma unroll
      for (int rd = 0; rd < 2; rd++) {
        gll16(kb + (size_t)(b * K_ + j0 + 64 + rd * 32 + row8) * 1024 + h * 64 + swz,
              &Ks[nxt][0] + rd * 2048 + w * 512);
        gll16(vbT + (size_t)((b * H_ + h) * 64 + rd * 32 + row8) * K_ + j0 + 64 + swz,
              &Vt[nxt][0] + rd * 2048 + w * 512);
      }
    }
#pragma unroll
    for (int rd = 0; rd < 2; rd++)
      gll16(pos + (size_t)(b * R_ + base0 + 64 * tt + 128 + rd * 32 + row8) * 64 + swz,
            Ps + (sc * 64 + rd * 32) * 64 + w * 512);

    // ---- QK^T: 16 rows x 64 keys ----
    f32x4 sqk[4];
#pragma unroll
    for (int kc = 0; kc < 4; kc++) {
      const short8 bK0 = *(const short8*)&Ks[cur][(kc * 16 + lr) * 64 + c0];
      const short8 bK1 = *(const short8*)&Ks[cur][(kc * 16 + lr) * 64 + c1];
      f32x4 z = {0.f, 0.f, 0.f, 0.f};
      z = mfma16(aQ0, bK0, z);
      sqk[kc] = mfma16(aQ1, bK1, z);
    }
    // ---- Q @ pos-band^T: 16 rows x 80 band cols, kept in registers ----
    f32x4 zp[5];
#pragma unroll
    for (int pc = 0; pc < 5; pc++) {
      const int xb = bw0 + pc * 16;
      const int slab = (xb >= 64) ? sb : sa;
      const int pb = slab * 64 + (xb & 63);
      const short8 bP0 = *(const short8*)&Ps[(pb + lr) * 64 + c0];
      const short8 bP1 = *(const short8*)&Ps[(pb + lr) * 64 + c1];
      f32x4 z = {0.f, 0.f, 0.f, 0.f};
      z = mfma16(aQ0, bP0, z);
      zp[pc] = mfma16(aQ1, bP1, z);
    }

    // ---- shuffle-based skew gather + max-free softmax ----
    const bool tail = (j0 + 63 > i0 + w * 16 + M_);  // wave-uniform
    float p[4][4];
#pragma unroll
    for (int r = 0; r < 4; r++) {
      const int iL = qd * 4 + r;
      const int d = 15 + lr - iL;                    // [0,30]
      const int srcl = qd * 16 + (d & 15);
      const bool hi = (d >> 4) & 1;
      float g0 = __shfl(zp[0][r], srcl, 64);
      float g1 = __shfl(zp[1][r], srcl, 64);
      float g2 = __shfl(zp[2][r], srcl, 64);
      float g3 = __shfl(zp[3][r], srcl, 64);
      float g4 = __shfl(zp[4][r], srcl, 64);
      float s0 = sqk[0][r] + (hi ? g1 : g0);
      float s1 = sqk[1][r] + (hi ? g2 : g1);
      float s2 = sqk[2][r] + (hi ? g3 : g2);
      float s3 = sqk[3][r] + (hi ? g4 : g3);
      if (tail) {
        const int key = j0 + lr, lim = i0 + w * 16 + iL + M_;
        if (key      > lim) s0 = NEG_BIG;
        if (key + 16 > lim) s1 = NEG_BIG;
        if (key + 32 > lim) s2 = NEG_BIG;
        if (key + 48 > lim) s3 = NEG_BIG;
      }
      p[0][r] = __expf(s0);
      p[1][r] = __expf(s1);
      p[2][r] = __expf(s2);
      p[3][r] = __expf(s3);
      lsum[r] += p[0][r] + p[1][r] + p[2][r] + p[3][r];
    }

    // ---- P -> wave-private LDS (padded stride 68) -> A-fragments ----
#pragma unroll
    for (int r = 0; r < 4; r++) {
      const int base = (qd * 4 + r) * 68 + lr;
      Pt[w][base +  0] = f2bf(p[0][r]);
      Pt[w][base + 16] = f2bf(p[1][r]);
      Pt[w][base + 32] = f2bf(p[2][r]);
      Pt[w][base + 48] = f2bf(p[3][r]);
    }
    __asm__ volatile("s_waitcnt lgkmcnt(0)" ::: "memory");
    const short8 aP0 = *(const short8*)&Pt[w][lr * 68 + qd * 8];
    const short8 aP1 = *(const short8*)&Pt[w][lr * 68 + 32 + qd * 8];

    // ---- P @ V ----
#pragma unroll
    for (int d2 = 0; d2 < 4; d2++) {
      const short8 bV0 = *(const short8*)&Vt[cur][(d2 * 16 + lr) * 64 + c0];
      const short8 bV1 = *(const short8*)&Vt[cur][(d2 * 16 + lr) * 64 + c1];
      accO[d2] = mfma16(aP0, bV0, accO[d2]);
      accO[d2] = mfma16(aP1, bV1, accO[d2]);
    }

    const int so = sa; sa = sb; sb = sc; sc = so;
    cur ^= 1;
  }

  // ---- epilogue: one 16-lane reduction of lsum, then normalize ----
  float inv[4];
#pragma unroll
  for (int r = 0; r < 4; r++) {
#pragma unroll
    for (int msk = 1; msk < 16; msk <<= 1) lsum[r] += __shfl_xor(lsum[r], msk, 64);
    inv[r] = 1.0f / lsum[r];
  }
#pragma unroll
  for (int d2 = 0; d2 < 4; d2++)
#pragma unroll
    for (int r = 0; r < 4; r++) {
      const int iG = i0 + w * 16 + qd * 4 + r;
      ab[(size_t)(b * S_ + iG) * 1024 + h * 64 + d2 * 16 + lr] = f2bf(accO[d2][r] * inv[r]);
    }
}

// ---------------- launch ----------------
extern "C" void kernel_launch(void* const* d_in, const int* in_sizes, int n_in,
                              void* d_out, int out_size, void* d_ws, size_t ws_size,
                              hipStream_t stream) {
  const float* hidden = (const float*)d_in[0];
  const float* pos    = (const float*)d_in[1];
  const float* memory = (const float*)d_in[2];
  // d_in[3] = mask (bool) — causality applied analytically, unused
  const float* Wq = (const float*)d_in[4];
  const float* Wk = (const float*)d_in[5];
  const float* Wv = (const float*)d_in[6];
  const float* Wo = (const float*)d_in[7];
  const float* gamma = (const float*)d_in[8];
  const float* beta  = (const float*)d_in[9];

  char* ws = (char*)d_ws;
  u16* cln  = (u16*)(ws);               // 8 MB
  u16* qb   = (u16*)(ws + 8388608);     // 4 MB (pre-scaled 1/32)
  u16* kb   = (u16*)(ws + 12582912);    // 8 MB
  u16* vbT  = (u16*)(ws + 20971520);    // 8 MB
  u16* ab   = (u16*)(ws + 29360128);    // 4 MB
  u16* WqT  = (u16*)(ws + 33554432);    // 4 x 2 MB contiguous (WqT|WkT|WvT|WoT)
  u16* WkT  = WqT + 1048576;
  u16* WvT  = WkT + 1048576;
  u16* WoT  = WvT + 1048576;
  u16* posb = (u16*)(ws + 41943040);    // ~1 MB

  prep_kernel<<<dim3(5632), 256, 0, stream>>>(
      hidden, memory, gamma, beta, cln,
      Wq, Wk, Wv, Wo, WqT, WkT, WvT, WoT, pos, posb);
  gemm_qkv_kernel<<<dim3(24, 32), 256, 0, stream>>>(cln, WqT, qb, kb, vbT);
  attn_kernel<<<dim3(S_ / 64, H_, B_), 256, 0, stream>>>(qb, kb, vbT, posb, ab);
  out_gemm_kernel<<<dim3(16, 16), 256, 0, stream>>>(ab, WoT, cln, (float*)d_out);
}